// Round 1
// baseline (1319.466 us; speedup 1.0000x reference)
//
#include <hip/hip_runtime.h>

// SOM layer on MI355X (gfx950).
// d2 = ||z||^2 - 2 z.p + ||p||^2 ; argmin over M ; output winner prototypes + idx.
// ||z||^2 is constant per row -> rank by s = p2[m] - 2*dot(z,p[m]).
// Accuracy: fp16 split-2 (hi+lo) MFMA => ~fp32-GEMM precision, needed to match
// numpy's fp32 argmin decisions (idx threshold is absmax => no flips allowed).

#define N_ROWS 32768
#define M_PROTO 4096
#define DIM 512

typedef _Float16 half8 __attribute__((ext_vector_type(8)));
typedef _Float16 half4_t __attribute__((ext_vector_type(4)));
typedef float f32x4 __attribute__((ext_vector_type(4)));

// ---------------- p2[m] = sum(p[m][:]^2), fp32 ----------------
__global__ __launch_bounds__(256) void p2_kernel(const float* __restrict__ p,
                                                 float* __restrict__ p2) {
    const int w = threadIdx.x >> 6, l = threadIdx.x & 63;
    const int m = blockIdx.x * 4 + w;
    const float4* p4 = (const float4*)p + (size_t)m * 128;
    float s = 0.f;
#pragma unroll
    for (int i = 0; i < 2; ++i) {
        float4 v = p4[l * 2 + i];
        s += v.x * v.x + v.y * v.y + v.z * v.z + v.w * v.w;
    }
#pragma unroll
    for (int mm = 1; mm < 64; mm <<= 1) s += __shfl_xor(s, mm);
    if (l == 0) p2[m] = s;
}

// ---------------- main fused GEMM-argmin + winner copy ----------------
// Block: 256 threads (4 waves). BM=64 z-rows per block, full M sweep in BN=128
// tiles, K-loop BK=64 (2 MFMA K-steps). Wave w owns cols w*32..w*32+31 of each
// BN tile (4x2 grid of 16x16 tiles). 3 MFMAs (hh, hl, lh) per tile per K=32.
__global__ __launch_bounds__(256) void som_kernel(const float* __restrict__ z,
                                                  const float* __restrict__ prot,
                                                  const float* __restrict__ p2,
                                                  float* __restrict__ out) {
    // LDS: fp16 split tiles, XOR-swizzled on 16B units within each 128B row.
    __shared__ __align__(16) _Float16 sZH[64 * 64];
    __shared__ __align__(16) _Float16 sZL[64 * 64];
    __shared__ __align__(16) _Float16 sPH[128 * 64];
    __shared__ __align__(16) _Float16 sPL[128 * 64];
    __shared__ float sMV[4][64];
    __shared__ int sMI[4][64];
    __shared__ int sFI[64];

    const int tid = threadIdx.x;
    const int w = tid >> 6;      // wave 0..3
    const int l = tid & 63;      // lane
    const int g = l >> 4;        // 4-lane-group row block (0..3)
    const int c = l & 15;        // col slot within 16x16 tile
    const int brow = blockIdx.x * 64;

    const float4* z4 = (const float4*)z;
    const float4* pr4 = (const float4*)prot;

    float minv[4][4];
    int mini[4][4];
#pragma unroll
    for (int i = 0; i < 4; ++i)
#pragma unroll
        for (int r = 0; r < 4; ++r) { minv[i][r] = 3.0e38f; mini[i][r] = 0; }

    for (int bcol = 0; bcol < M_PROTO; bcol += 128) {
        f32x4 acc[4][2];
#pragma unroll
        for (int i = 0; i < 4; ++i)
#pragma unroll
            for (int jt = 0; jt < 2; ++jt) acc[i][jt] = (f32x4){0.f, 0.f, 0.f, 0.f};

        for (int kt = 0; kt < 8; ++kt) {
            __syncthreads();
            // ---- stage A (z tile, scaled by -2, split hi/lo) : 64x64 f32 ----
#pragma unroll
            for (int it = 0; it < 4; ++it) {
                int q = it * 256 + tid;          // float4 id, 0..1023
                int row = q >> 4, kq = q & 15;   // row 0..63, quad 0..15
                float4 v = z4[(size_t)(brow + row) * 128 + kt * 16 + kq];
                float x0 = -2.f * v.x, x1 = -2.f * v.y, x2 = -2.f * v.z, x3 = -2.f * v.w;
                _Float16 h0 = (_Float16)x0, h1 = (_Float16)x1;
                _Float16 h2 = (_Float16)x2, h3 = (_Float16)x3;
                half4_t hv = {h0, h1, h2, h3};
                half4_t lv = {(_Float16)(x0 - (float)h0), (_Float16)(x1 - (float)h1),
                              (_Float16)(x2 - (float)h2), (_Float16)(x3 - (float)h3)};
                int addr = row * 64 + (((kq >> 1) ^ (row & 7)) << 3) + ((kq & 1) << 2);
                *(half4_t*)&sZH[addr] = hv;
                *(half4_t*)&sZL[addr] = lv;
            }
            // ---- stage B (prototype tile, split hi/lo) : 128x64 f32 ----
#pragma unroll
            for (int it = 0; it < 8; ++it) {
                int q = it * 256 + tid;          // 0..2047
                int row = q >> 4, kq = q & 15;   // row 0..127
                float4 v = pr4[(size_t)(bcol + row) * 128 + kt * 16 + kq];
                _Float16 h0 = (_Float16)v.x, h1 = (_Float16)v.y;
                _Float16 h2 = (_Float16)v.z, h3 = (_Float16)v.w;
                half4_t hv = {h0, h1, h2, h3};
                half4_t lv = {(_Float16)(v.x - (float)h0), (_Float16)(v.y - (float)h1),
                              (_Float16)(v.z - (float)h2), (_Float16)(v.w - (float)h3)};
                int addr = row * 64 + (((kq >> 1) ^ (row & 7)) << 3) + ((kq & 1) << 2);
                *(half4_t*)&sPH[addr] = hv;
                *(half4_t*)&sPL[addr] = lv;
            }
            __syncthreads();
            // ---- compute: 2 K-steps of 32, 24 MFMA each ----
#pragma unroll
            for (int ks = 0; ks < 2; ++ks) {
                half8 ah[4], al[4], bh[2], bl[2];
#pragma unroll
                for (int i = 0; i < 4; ++i) {
                    int row = i * 16 + c;
                    int addr = row * 64 + (((ks * 4 + g) ^ (row & 7)) << 3);
                    ah[i] = *(half8*)&sZH[addr];
                    al[i] = *(half8*)&sZL[addr];
                }
#pragma unroll
                for (int jt = 0; jt < 2; ++jt) {
                    int row = w * 32 + jt * 16 + c;
                    int addr = row * 64 + (((ks * 4 + g) ^ (row & 7)) << 3);
                    bh[jt] = *(half8*)&sPH[addr];
                    bl[jt] = *(half8*)&sPL[addr];
                }
#pragma unroll
                for (int i = 0; i < 4; ++i)
#pragma unroll
                    for (int jt = 0; jt < 2; ++jt) {
                        acc[i][jt] = __builtin_amdgcn_mfma_f32_16x16x32_f16(ah[i], bh[jt], acc[i][jt], 0, 0, 0);
                        acc[i][jt] = __builtin_amdgcn_mfma_f32_16x16x32_f16(ah[i], bl[jt], acc[i][jt], 0, 0, 0);
                        acc[i][jt] = __builtin_amdgcn_mfma_f32_16x16x32_f16(al[i], bh[jt], acc[i][jt], 0, 0, 0);
                    }
            }
        }
        // ---- epilogue: s = acc + p2[col]; running (min, idx) per (i,r) ----
#pragma unroll
        for (int jt = 0; jt < 2; ++jt) {
            int colg = bcol + w * 32 + jt * 16 + c;
            float pv = p2[colg];
#pragma unroll
            for (int i = 0; i < 4; ++i)
#pragma unroll
                for (int r = 0; r < 4; ++r) {
                    float s = acc[i][jt][r] + pv;
                    if (s < minv[i][r] || (s == minv[i][r] && colg < mini[i][r])) {
                        minv[i][r] = s;
                        mini[i][r] = colg;
                    }
                }
        }
    }

    // ---- cross-lane column reduce (16 lanes share a row) ----
#pragma unroll
    for (int i = 0; i < 4; ++i)
#pragma unroll
        for (int r = 0; r < 4; ++r) {
            float v = minv[i][r];
            int id = mini[i][r];
#pragma unroll
            for (int mm = 1; mm < 16; mm <<= 1) {
                float ov = __shfl_xor(v, mm);
                int oi = __shfl_xor(id, mm);
                if (ov < v || (ov == v && oi < id)) { v = ov; id = oi; }
            }
            if (c == 0) {
                int rl = i * 16 + g * 4 + r;   // local row 0..63
                sMV[w][rl] = v;
                sMI[w][rl] = id;
            }
        }
    __syncthreads();

    // ---- cross-wave merge (4 waves cover disjoint col sets) ----
    if (tid < 64) {
        float v = sMV[0][tid];
        int id = sMI[0][tid];
#pragma unroll
        for (int ww = 1; ww < 4; ++ww) {
            float ov = sMV[ww][tid];
            int oi = sMI[ww][tid];
            if (ov < v || (ov == v && oi < id)) { v = ov; id = oi; }
        }
        sFI[tid] = id;
        out[(size_t)N_ROWS * DIM + brow + tid] = (float)id;  // idx as float
    }
    __syncthreads();

    // ---- winner prototype copy: 64 rows x 128 float4 ----
    float4* out4 = (float4*)out;
#pragma unroll 4
    for (int it = 0; it < 32; ++it) {
        int q = it * 256 + tid;
        int row = q >> 7, qk = q & 127;
        int fi = sFI[row];
        out4[(size_t)(brow + row) * 128 + qk] = pr4[(size_t)fi * 128 + qk];
    }
}

extern "C" void kernel_launch(void* const* d_in, const int* in_sizes, int n_in,
                              void* d_out, int out_size, void* d_ws, size_t ws_size,
                              hipStream_t stream) {
    const float* z = (const float*)d_in[0];
    const float* prot = (const float*)d_in[1];
    float* p2 = (float*)d_ws;  // 4096 floats = 16 KB scratch

    p2_kernel<<<M_PROTO / 4, 256, 0, stream>>>(prot, p2);
    som_kernel<<<N_ROWS / 64, 256, 0, stream>>>(z, prot, p2, (float*)d_out);
}

// Round 2
// 669.491 us; speedup vs baseline: 1.9708x; 1.9708x over previous
//
#include <hip/hip_runtime.h>

// SOM layer on MI355X (gfx950).  R2: precompute fp16 split-2 (hi/lo) tiles of
// z (scaled -2) and prototypes into d_ws, laid out as pre-swizzled LDS images;
// main kernel stages tiles via global_load_lds (16B) and runs the MFMA-argmin.
// Rank by s = p2[m] - 2*dot(z,p[m]) (||z||^2 constant per row).
// Accuracy: 3-product split MFMA (hh+hl+lh) == fp32-GEMM precision (R1: absmax 0.0).

#define N_ROWS 32768
#define M_PROTO 4096
#define DIM 512

typedef _Float16 half8 __attribute__((ext_vector_type(8)));
typedef _Float16 half4_t __attribute__((ext_vector_type(4)));
typedef float f32x4 __attribute__((ext_vector_type(4)));

__device__ __forceinline__ void gl_lds16(const void* g, void* l) {
    __builtin_amdgcn_global_load_lds(
        (const __attribute__((address_space(1))) unsigned int*)g,
        (__attribute__((address_space(3))) unsigned int*)l, 16, 0, 0);
}

// ---------------- p2[m] = sum(p[m][:]^2), fp32 ----------------
__global__ __launch_bounds__(256) void p2_kernel(const float* __restrict__ p,
                                                 float* __restrict__ p2) {
    const int w = threadIdx.x >> 6, l = threadIdx.x & 63;
    const int m = blockIdx.x * 4 + w;
    const float4* p4 = (const float4*)p + (size_t)m * 128;
    float s = 0.f;
#pragma unroll
    for (int i = 0; i < 2; ++i) {
        float4 v = p4[l * 2 + i];
        s += v.x * v.x + v.y * v.y + v.z * v.z + v.w * v.w;
    }
#pragma unroll
    for (int mm = 1; mm < 64; mm <<= 1) s += __shfl_xor(s, mm);
    if (l == 0) p2[m] = s;
}

// ---------------- conversion: fp32 -> split fp16 pre-swizzled tiles ----------
// Tile = 128 rows x 64 k-halves (8192 halves = 16 KB), swizzle:
//   addr = row*64 + (((kq>>1)^(row&7))<<3) + ((kq&1)<<2)   (kq = float4 id 0..15)
// z tiles: (blk 0..255, kt 0..7), rows = blk*128+row, scaled by -2.
__global__ __launch_bounds__(256) void conv_z_kernel(const float* __restrict__ z,
                                                     _Float16* __restrict__ zh,
                                                     _Float16* __restrict__ zl) {
    const int tile = blockIdx.x;         // blk*8 + kt
    const int blk = tile >> 3, kt = tile & 7;
    const float4* z4 = (const float4*)z;
    const size_t tb = (size_t)tile * 8192;
#pragma unroll
    for (int it = 0; it < 8; ++it) {
        int q = it * 256 + threadIdx.x;  // 0..2047
        int row = q >> 4, kq = q & 15;
        float4 v = z4[(size_t)(blk * 128 + row) * 128 + kt * 16 + kq];
        float x0 = -2.f * v.x, x1 = -2.f * v.y, x2 = -2.f * v.z, x3 = -2.f * v.w;
        _Float16 h0 = (_Float16)x0, h1 = (_Float16)x1;
        _Float16 h2 = (_Float16)x2, h3 = (_Float16)x3;
        half4_t hv = {h0, h1, h2, h3};
        half4_t lv = {(_Float16)(x0 - (float)h0), (_Float16)(x1 - (float)h1),
                      (_Float16)(x2 - (float)h2), (_Float16)(x3 - (float)h3)};
        int addr = row * 64 + (((kq >> 1) ^ (row & 7)) << 3) + ((kq & 1) << 2);
        *(half4_t*)&zh[tb + addr] = hv;
        *(half4_t*)&zl[tb + addr] = lv;
    }
}

// p tiles: (bi 0..31, kt 0..7), rows = bi*128+row, no scale.
__global__ __launch_bounds__(256) void conv_p_kernel(const float* __restrict__ p,
                                                     _Float16* __restrict__ ph,
                                                     _Float16* __restrict__ pl) {
    const int tile = blockIdx.x;         // bi*8 + kt
    const int bi = tile >> 3, kt = tile & 7;
    const float4* p4 = (const float4*)p;
    const size_t tb = (size_t)tile * 8192;
#pragma unroll
    for (int it = 0; it < 8; ++it) {
        int q = it * 256 + threadIdx.x;
        int row = q >> 4, kq = q & 15;
        float4 v = p4[(size_t)(bi * 128 + row) * 128 + kt * 16 + kq];
        _Float16 h0 = (_Float16)v.x, h1 = (_Float16)v.y;
        _Float16 h2 = (_Float16)v.z, h3 = (_Float16)v.w;
        half4_t hv = {h0, h1, h2, h3};
        half4_t lv = {(_Float16)(v.x - (float)h0), (_Float16)(v.y - (float)h1),
                      (_Float16)(v.z - (float)h2), (_Float16)(v.w - (float)h3)};
        int addr = row * 64 + (((kq >> 1) ^ (row & 7)) << 3) + ((kq & 1) << 2);
        *(half4_t*)&ph[tb + addr] = hv;
        *(half4_t*)&pl[tb + addr] = lv;
    }
}

// ---------------- main fused GEMM-argmin + winner copy (fast path) ----------
// 512 threads (8 waves, 2 row x 4 col). BM=128 rows/block (256 blocks),
// BN=128 cols/tile, BK=64. Wave (wr,wc) owns rows wr*64..+63, cols wc*32..+31.
// Per K-step ks: 12 ds_read_b128 feed 24 MFMA (3 split products x 4x2 tiles).
__global__ __launch_bounds__(512, 2) void som_main(
    const _Float16* __restrict__ zh, const _Float16* __restrict__ zl,
    const _Float16* __restrict__ ph, const _Float16* __restrict__ pl,
    const float* __restrict__ p2, const float* __restrict__ prot,
    float* __restrict__ out) {
    __shared__ __align__(16) _Float16 sZH[8192];
    __shared__ __align__(16) _Float16 sZL[8192];
    __shared__ __align__(16) _Float16 sPH[8192];
    __shared__ __align__(16) _Float16 sPL[8192];
    __shared__ float sMV[8][64];
    __shared__ int sMI[8][64];
    __shared__ int sFI[128];

    const int tid = threadIdx.x;
    const int w = tid >> 6, l = tid & 63;
    const int g = l >> 4, c = l & 15;
    const int wr = w >> 2, wc = w & 3;
    const int blk = blockIdx.x, brow = blk * 128;

    float minv[4][4];
    int mini[4][4];
#pragma unroll
    for (int i = 0; i < 4; ++i)
#pragma unroll
        for (int r = 0; r < 4; ++r) { minv[i][r] = 3.0e38f; mini[i][r] = 0; }

    for (int bi = 0; bi < 32; ++bi) {
        f32x4 acc[4][2];
#pragma unroll
        for (int i = 0; i < 4; ++i)
#pragma unroll
            for (int jt = 0; jt < 2; ++jt) acc[i][jt] = (f32x4){0.f, 0.f, 0.f, 0.f};

        for (int kt = 0; kt < 8; ++kt) {
            __syncthreads();  // previous compute done before overwriting LDS
            {
                const _Float16* sz_h = zh + ((size_t)(blk * 8 + kt)) * 8192;
                const _Float16* sz_l = zl + ((size_t)(blk * 8 + kt)) * 8192;
                const _Float16* sp_h = ph + ((size_t)(bi * 8 + kt)) * 8192;
                const _Float16* sp_l = pl + ((size_t)(bi * 8 + kt)) * 8192;
                const int c0 = (w * 2 + 0) * 512, c1 = (w * 2 + 1) * 512;  // halves
                const int lo = l * 8;                                      // halves
                gl_lds16(sz_h + c0 + lo, sZH + c0);
                gl_lds16(sz_h + c1 + lo, sZH + c1);
                gl_lds16(sz_l + c0 + lo, sZL + c0);
                gl_lds16(sz_l + c1 + lo, sZL + c1);
                gl_lds16(sp_h + c0 + lo, sPH + c0);
                gl_lds16(sp_h + c1 + lo, sPH + c1);
                gl_lds16(sp_l + c0 + lo, sPL + c0);
                gl_lds16(sp_l + c1 + lo, sPL + c1);
            }
            __syncthreads();  // compiler drains vmcnt(0) before barrier

#pragma unroll
            for (int ks = 0; ks < 2; ++ks) {
                half8 ah[4], al[4], bh[2], bl[2];
#pragma unroll
                for (int i = 0; i < 4; ++i) {
                    int row = wr * 64 + i * 16 + c;
                    int addr = row * 64 + (((ks * 4 + g) ^ (row & 7)) << 3);
                    ah[i] = *(half8*)&sZH[addr];
                    al[i] = *(half8*)&sZL[addr];
                }
#pragma unroll
                for (int jt = 0; jt < 2; ++jt) {
                    int row = wc * 32 + jt * 16 + c;
                    int addr = row * 64 + (((ks * 4 + g) ^ (row & 7)) << 3);
                    bh[jt] = *(half8*)&sPH[addr];
                    bl[jt] = *(half8*)&sPL[addr];
                }
#pragma unroll
                for (int i = 0; i < 4; ++i)
#pragma unroll
                    for (int jt = 0; jt < 2; ++jt) {
                        acc[i][jt] = __builtin_amdgcn_mfma_f32_16x16x32_f16(ah[i], bh[jt], acc[i][jt], 0, 0, 0);
                        acc[i][jt] = __builtin_amdgcn_mfma_f32_16x16x32_f16(ah[i], bl[jt], acc[i][jt], 0, 0, 0);
                        acc[i][jt] = __builtin_amdgcn_mfma_f32_16x16x32_f16(al[i], bh[jt], acc[i][jt], 0, 0, 0);
                    }
            }
        }
        // ---- epilogue: s = acc + p2[col]; running (min, idx) ----
#pragma unroll
        for (int jt = 0; jt < 2; ++jt) {
            int colg = bi * 128 + wc * 32 + jt * 16 + c;
            float pv = p2[colg];
#pragma unroll
            for (int i = 0; i < 4; ++i)
#pragma unroll
                for (int r = 0; r < 4; ++r) {
                    float s = acc[i][jt][r] + pv;
                    if (s < minv[i][r] || (s == minv[i][r] && colg < mini[i][r])) {
                        minv[i][r] = s;
                        mini[i][r] = colg;
                    }
                }
        }
    }

    // ---- cross-lane column reduce (16 lanes share a row) ----
#pragma unroll
    for (int i = 0; i < 4; ++i)
#pragma unroll
        for (int r = 0; r < 4; ++r) {
            float v = minv[i][r];
            int id = mini[i][r];
#pragma unroll
            for (int mm = 1; mm < 16; mm <<= 1) {
                float ov = __shfl_xor(v, mm);
                int oi = __shfl_xor(id, mm);
                if (ov < v || (ov == v && oi < id)) { v = ov; id = oi; }
            }
            if (c == 0) {
                sMV[w][i * 16 + g * 4 + r] = v;
                sMI[w][i * 16 + g * 4 + r] = id;
            }
        }
    __syncthreads();

    // ---- cross-wave merge: 4 waves (same wr) cover disjoint cols ----
    if (tid < 128) {
        int wrr = tid >> 6, lrow = tid & 63;
        float v = sMV[wrr * 4][lrow];
        int id = sMI[wrr * 4][lrow];
#pragma unroll
        for (int ww = 1; ww < 4; ++ww) {
            float ov = sMV[wrr * 4 + ww][lrow];
            int oi = sMI[wrr * 4 + ww][lrow];
            if (ov < v || (ov == v && oi < id)) { v = ov; id = oi; }
        }
        sFI[tid] = id;
        out[(size_t)N_ROWS * DIM + brow + tid] = (float)id;
    }
    __syncthreads();

    // ---- winner prototype copy: 128 rows x 128 float4 ----
    const float4* pr4 = (const float4*)prot;
    float4* out4 = (float4*)out;
#pragma unroll 4
    for (int it = 0; it < 32; ++it) {
        int q = it * 512 + tid;
        int row = q >> 7, qk = q & 127;
        int fi = sFI[row];
        out4[(size_t)(brow + row) * 128 + qk] = pr4[(size_t)fi * 128 + qk];
    }
}

// ---------------- fallback (R1 kernel, used only if ws too small) -----------
__global__ __launch_bounds__(256) void som_fallback(const float* __restrict__ z,
                                                    const float* __restrict__ prot,
                                                    const float* __restrict__ p2,
                                                    float* __restrict__ out) {
    __shared__ __align__(16) _Float16 sZH[64 * 64];
    __shared__ __align__(16) _Float16 sZL[64 * 64];
    __shared__ __align__(16) _Float16 sPH[128 * 64];
    __shared__ __align__(16) _Float16 sPL[128 * 64];
    __shared__ float sMV[4][64];
    __shared__ int sMI[4][64];
    __shared__ int sFI[64];

    const int tid = threadIdx.x;
    const int w = tid >> 6, l = tid & 63;
    const int g = l >> 4, c = l & 15;
    const int brow = blockIdx.x * 64;
    const float4* z4 = (const float4*)z;
    const float4* pr4 = (const float4*)prot;

    float minv[4][4];
    int mini[4][4];
#pragma unroll
    for (int i = 0; i < 4; ++i)
#pragma unroll
        for (int r = 0; r < 4; ++r) { minv[i][r] = 3.0e38f; mini[i][r] = 0; }

    for (int bcol = 0; bcol < M_PROTO; bcol += 128) {
        f32x4 acc[4][2];
#pragma unroll
        for (int i = 0; i < 4; ++i)
#pragma unroll
            for (int jt = 0; jt < 2; ++jt) acc[i][jt] = (f32x4){0.f, 0.f, 0.f, 0.f};
        for (int kt = 0; kt < 8; ++kt) {
            __syncthreads();
#pragma unroll
            for (int it = 0; it < 4; ++it) {
                int q = it * 256 + tid;
                int row = q >> 4, kq = q & 15;
                float4 v = z4[(size_t)(brow + row) * 128 + kt * 16 + kq];
                float x0 = -2.f * v.x, x1 = -2.f * v.y, x2 = -2.f * v.z, x3 = -2.f * v.w;
                _Float16 h0 = (_Float16)x0, h1 = (_Float16)x1;
                _Float16 h2 = (_Float16)x2, h3 = (_Float16)x3;
                half4_t hv = {h0, h1, h2, h3};
                half4_t lv = {(_Float16)(x0 - (float)h0), (_Float16)(x1 - (float)h1),
                              (_Float16)(x2 - (float)h2), (_Float16)(x3 - (float)h3)};
                int addr = row * 64 + (((kq >> 1) ^ (row & 7)) << 3) + ((kq & 1) << 2);
                *(half4_t*)&sZH[addr] = hv;
                *(half4_t*)&sZL[addr] = lv;
            }
#pragma unroll
            for (int it = 0; it < 8; ++it) {
                int q = it * 256 + tid;
                int row = q >> 4, kq = q & 15;
                float4 v = pr4[(size_t)(bcol + row) * 128 + kt * 16 + kq];
                _Float16 h0 = (_Float16)v.x, h1 = (_Float16)v.y;
                _Float16 h2 = (_Float16)v.z, h3 = (_Float16)v.w;
                half4_t hv = {h0, h1, h2, h3};
                half4_t lv = {(_Float16)(v.x - (float)h0), (_Float16)(v.y - (float)h1),
                              (_Float16)(v.z - (float)h2), (_Float16)(v.w - (float)h3)};
                int addr = row * 64 + (((kq >> 1) ^ (row & 7)) << 3) + ((kq & 1) << 2);
                *(half4_t*)&sPH[addr] = hv;
                *(half4_t*)&sPL[addr] = lv;
            }
            __syncthreads();
#pragma unroll
            for (int ks = 0; ks < 2; ++ks) {
                half8 ah[4], al[4], bh[2], bl[2];
#pragma unroll
                for (int i = 0; i < 4; ++i) {
                    int row = i * 16 + c;
                    int addr = row * 64 + (((ks * 4 + g) ^ (row & 7)) << 3);
                    ah[i] = *(half8*)&sZH[addr];
                    al[i] = *(half8*)&sZL[addr];
                }
#pragma unroll
                for (int jt = 0; jt < 2; ++jt) {
                    int row = w * 32 + jt * 16 + c;
                    int addr = row * 64 + (((ks * 4 + g) ^ (row & 7)) << 3);
                    bh[jt] = *(half8*)&sPH[addr];
                    bl[jt] = *(half8*)&sPL[addr];
                }
#pragma unroll
                for (int i = 0; i < 4; ++i)
#pragma unroll
                    for (int jt = 0; jt < 2; ++jt) {
                        acc[i][jt] = __builtin_amdgcn_mfma_f32_16x16x32_f16(ah[i], bh[jt], acc[i][jt], 0, 0, 0);
                        acc[i][jt] = __builtin_amdgcn_mfma_f32_16x16x32_f16(ah[i], bl[jt], acc[i][jt], 0, 0, 0);
                        acc[i][jt] = __builtin_amdgcn_mfma_f32_16x16x32_f16(al[i], bh[jt], acc[i][jt], 0, 0, 0);
                    }
            }
        }
#pragma unroll
        for (int jt = 0; jt < 2; ++jt) {
            int colg = bcol + w * 32 + jt * 16 + c;
            float pv = p2[colg];
#pragma unroll
            for (int i = 0; i < 4; ++i)
#pragma unroll
                for (int r = 0; r < 4; ++r) {
                    float s = acc[i][jt][r] + pv;
                    if (s < minv[i][r] || (s == minv[i][r] && colg < mini[i][r])) {
                        minv[i][r] = s;
                        mini[i][r] = colg;
                    }
                }
        }
    }
#pragma unroll
    for (int i = 0; i < 4; ++i)
#pragma unroll
        for (int r = 0; r < 4; ++r) {
            float v = minv[i][r];
            int id = mini[i][r];
#pragma unroll
            for (int mm = 1; mm < 16; mm <<= 1) {
                float ov = __shfl_xor(v, mm);
                int oi = __shfl_xor(id, mm);
                if (ov < v || (ov == v && oi < id)) { v = ov; id = oi; }
            }
            if (c == 0) {
                sMV[w][i * 16 + g * 4 + r] = v;
                sMI[w][i * 16 + g * 4 + r] = id;
            }
        }
    __syncthreads();
    if (tid < 64) {
        float v = sMV[0][tid];
        int id = sMI[0][tid];
#pragma unroll
        for (int ww = 1; ww < 4; ++ww) {
            float ov = sMV[ww][tid];
            int oi = sMI[ww][tid];
            if (ov < v || (ov == v && oi < id)) { v = ov; id = oi; }
        }
        sFI[tid] = id;
        out[(size_t)N_ROWS * DIM + brow + tid] = (float)id;
    }
    __syncthreads();
    float4* out4 = (float4*)out;
#pragma unroll 4
    for (int it = 0; it < 32; ++it) {
        int q = it * 256 + tid;
        int row = q >> 7, qk = q & 127;
        int fi = sFI[row];
        out4[(size_t)(brow + row) * 128 + qk] = pr4[(size_t)fi * 128 + qk];
    }
}

extern "C" void kernel_launch(void* const* d_in, const int* in_sizes, int n_in,
                              void* d_out, int out_size, void* d_ws, size_t ws_size,
                              hipStream_t stream) {
    const float* z = (const float*)d_in[0];
    const float* prot = (const float*)d_in[1];
    char* base = (char*)d_ws;
    float* p2 = (float*)base;  // 16 KB

    const size_t NEED = 16384          // p2
                      + 8388608        // ph+pl (4 MB each)
                      + 67108864;      // zh+zl (32 MB each)

    p2_kernel<<<M_PROTO / 4, 256, 0, stream>>>(prot, p2);

    if (ws_size >= NEED) {
        _Float16* ph = (_Float16*)(base + 16384);
        _Float16* pl = (_Float16*)(base + 16384 + 4194304);
        _Float16* zh = (_Float16*)(base + 16384 + 8388608);
        _Float16* zl = (_Float16*)(base + 16384 + 8388608 + 33554432);
        conv_p_kernel<<<256, 256, 0, stream>>>(prot, ph, pl);
        conv_z_kernel<<<2048, 256, 0, stream>>>(z, zh, zl);
        som_main<<<N_ROWS / 128, 512, 0, stream>>>(zh, zl, ph, pl, p2, prot, (float*)d_out);
    } else {
        som_fallback<<<N_ROWS / 64, 256, 0, stream>>>(z, prot, p2, (float*)d_out);
    }
}

// Round 3
// 527.837 us; speedup vs baseline: 2.4998x; 1.2684x over previous
//
#include <hip/hip_runtime.h>

// SOM layer on MI355X (gfx950).  R3: z held in REGISTERS full-K (128 VGPRs of
// fp16 split-2 fragments per wave, loaded once from a fragment-ordered ws
// image); only p streams through double-buffered LDS with a 2-phase pipeline
// (stage-next || compute-current, one barrier per K-step). All blocks sweep p
// tiles in the same order -> broadcast, XCD-L2-served.
// Rank by s = p2[m] - 2*dot(z,p[m]); accuracy via 3-product split MFMA
// (hh+hl+lh) == fp32-GEMM precision (R1/R2: absmax 0.0).

#define N_ROWS 32768
#define M_PROTO 4096
#define DIM 512

typedef _Float16 half8 __attribute__((ext_vector_type(8)));
typedef _Float16 half4_t __attribute__((ext_vector_type(4)));
typedef float f32x4 __attribute__((ext_vector_type(4)));

__device__ __forceinline__ void gl_lds16(const void* g, void* l) {
    __builtin_amdgcn_global_load_lds(
        (const __attribute__((address_space(1))) unsigned int*)g,
        (__attribute__((address_space(3))) unsigned int*)l, 16, 0, 0);
}

// ---------------- p2[m] = sum(p[m][:]^2), fp32 ----------------
__global__ __launch_bounds__(256) void p2_kernel(const float* __restrict__ p,
                                                 float* __restrict__ p2) {
    const int w = threadIdx.x >> 6, l = threadIdx.x & 63;
    const int m = blockIdx.x * 4 + w;
    const float4* p4 = (const float4*)p + (size_t)m * 128;
    float s = 0.f;
#pragma unroll
    for (int i = 0; i < 2; ++i) {
        float4 v = p4[l * 2 + i];
        s += v.x * v.x + v.y * v.y + v.z * v.z + v.w * v.w;
    }
#pragma unroll
    for (int mm = 1; mm < 64; mm <<= 1) s += __shfl_xor(s, mm);
    if (l == 0) p2[m] = s;
}

// ---------------- conv_p: fp32 -> split fp16 pre-swizzled LDS-image tiles ----
// Tile = 128 rows x 64 k-halves (16 KB); addr = row*64 + (((kq>>1)^(row&7))<<3)
// + ((kq&1)<<2).  Tiles ordered tile = bi*8 + kt.
__global__ __launch_bounds__(256) void conv_p_kernel(const float* __restrict__ p,
                                                     _Float16* __restrict__ ph,
                                                     _Float16* __restrict__ pl) {
    const int tile = blockIdx.x;         // bi*8 + kt
    const int bi = tile >> 3, kt = tile & 7;
    const float4* p4 = (const float4*)p;
    const size_t tb = (size_t)tile * 8192;
#pragma unroll
    for (int it = 0; it < 8; ++it) {
        int q = it * 256 + threadIdx.x;
        int row = q >> 4, kq = q & 15;
        float4 v = p4[(size_t)(bi * 128 + row) * 128 + kt * 16 + kq];
        _Float16 h0 = (_Float16)v.x, h1 = (_Float16)v.y;
        _Float16 h2 = (_Float16)v.z, h3 = (_Float16)v.w;
        half4_t hv = {h0, h1, h2, h3};
        half4_t lv = {(_Float16)(v.x - (float)h0), (_Float16)(v.y - (float)h1),
                      (_Float16)(v.z - (float)h2), (_Float16)(v.w - (float)h3)};
        int addr = row * 64 + (((kq >> 1) ^ (row & 7)) << 3) + ((kq & 1) << 2);
        *(half4_t*)&ph[tb + addr] = hv;
        *(half4_t*)&pl[tb + addr] = lv;
    }
}

// ---------------- conv_z: fp32 -> per-wave A-fragment image (scaled -2) ------
// slot = (S*16 + ks)*64 + lane   (S = 16-row stripe 0..2047, ks = K/32 step)
// content half8 = -2*z[S*16 + (lane&15)][ks*32 + (lane>>4)*8 + 0..7], hi|lo.
__global__ __launch_bounds__(256) void conv_z_kernel(const float* __restrict__ z,
                                                     half8* __restrict__ zh,
                                                     half8* __restrict__ zl) {
    const float4* z4 = (const float4*)z;
#pragma unroll
    for (int it = 0; it < 8; ++it) {
        int slot = it * 262144 + blockIdx.x * 256 + threadIdx.x;
        int lane = slot & 63, sk = slot >> 6;      // sk = S*16+ks
        int c = lane & 15, g = (lane >> 4) & 3;
        int S = sk >> 4, ks = sk & 15;
        int rowi = S * 16 + c;
        float4 v0 = z4[(size_t)rowi * 128 + ks * 8 + g * 2 + 0];
        float4 v1 = z4[(size_t)rowi * 128 + ks * 8 + g * 2 + 1];
        float x0 = -2.f * v0.x, x1 = -2.f * v0.y, x2 = -2.f * v0.z, x3 = -2.f * v0.w;
        float x4 = -2.f * v1.x, x5 = -2.f * v1.y, x6 = -2.f * v1.z, x7 = -2.f * v1.w;
        _Float16 h0 = (_Float16)x0, h1 = (_Float16)x1, h2 = (_Float16)x2, h3 = (_Float16)x3;
        _Float16 h4 = (_Float16)x4, h5 = (_Float16)x5, h6 = (_Float16)x6, h7 = (_Float16)x7;
        half8 hv = {h0, h1, h2, h3, h4, h5, h6, h7};
        half8 lv = {(_Float16)(x0 - (float)h0), (_Float16)(x1 - (float)h1),
                    (_Float16)(x2 - (float)h2), (_Float16)(x3 - (float)h3),
                    (_Float16)(x4 - (float)h4), (_Float16)(x5 - (float)h5),
                    (_Float16)(x6 - (float)h6), (_Float16)(x7 - (float)h7)};
        zh[slot] = hv;
        zl[slot] = lv;
    }
}

// ---------------- main: z-in-regs MFMA-argmin, p dbuf-pipelined -------------
// 512 threads (8 waves), each wave owns 16 z-rows (stripe S=blk*8+w) full-K in
// regs; block computes 128 rows x all 4096 cols. Per K-step: 16 ds_read_b128
// (B frags, shared p LDS) feed 24 MFMA; next p tile prefetched via
// global_load_lds into the other buffer (parity = kt&1, compile-time).
__global__ __launch_bounds__(512, 2) void som_main(
    const half8* __restrict__ zh, const half8* __restrict__ zl,
    const _Float16* __restrict__ ph, const _Float16* __restrict__ pl,
    const float* __restrict__ p2, const float* __restrict__ prot,
    float* __restrict__ out) {
    __shared__ __align__(16) _Float16 sPH[2][8192];
    __shared__ __align__(16) _Float16 sPL[2][8192];
    __shared__ int sFI[128];

    const int tid = threadIdx.x;
    const int w = tid >> 6, l = tid & 63;
    const int g = l >> 4, c = l & 15;
    const int blk = blockIdx.x, brow = blk * 128;
    const int S = blk * 8 + w;

    // ---- load full-K z fragments into registers (one pass, coalesced) ----
    half8 za[16], zb[16];
#pragma unroll
    for (int ks = 0; ks < 16; ++ks) {
        size_t slot = (size_t)(S * 16 + ks) * 64 + l;
        za[ks] = zh[slot];
        zb[ks] = zl[slot];
    }

    // ---- prologue: stage p tile 0 into buffer 0 ----
    {
        const int lo = l * 8;
#pragma unroll
        for (int j = 0; j < 2; ++j) {
            int c0 = (w * 2 + j) * 512;
            gl_lds16(ph + c0 + lo, &sPH[0][c0]);
            gl_lds16(pl + c0 + lo, &sPL[0][c0]);
        }
    }
    __syncthreads();

    float minv[4];
    int mini[4];
#pragma unroll
    for (int r = 0; r < 4; ++r) { minv[r] = 3.0e38f; mini[r] = 0; }

    for (int bi = 0; bi < 32; ++bi) {
        f32x4 acc[8];
#pragma unroll
        for (int jt = 0; jt < 8; ++jt) acc[jt] = (f32x4){0.f, 0.f, 0.f, 0.f};

#pragma unroll
        for (int kt = 0; kt < 8; ++kt) {
            const int cur = kt & 1;            // bi*8 even => parity is kt&1
            const int tp = bi * 8 + kt;
            // ---- prefetch next tile into the other buffer ----
            if (tp < 255) {
                const _Float16* sph = ph + (size_t)(tp + 1) * 8192;
                const _Float16* spl = pl + (size_t)(tp + 1) * 8192;
                const int lo = l * 8;
#pragma unroll
                for (int j = 0; j < 2; ++j) {
                    int c0 = (w * 2 + j) * 512;
                    gl_lds16(sph + c0 + lo, &sPH[cur ^ 1][c0]);
                    gl_lds16(spl + c0 + lo, &sPL[cur ^ 1][c0]);
                }
            }
            // ---- compute current tile: 2 k-slices x (16 ds_read + 24 MFMA) ----
#pragma unroll
            for (int ksl = 0; ksl < 2; ++ksl) {
                const int ks = kt * 2 + ksl;
#pragma unroll
                for (int jt = 0; jt < 8; ++jt) {
                    int row = jt * 16 + c;
                    int addr = row * 64 + (((ksl * 4 + g) ^ (row & 7)) << 3);
                    half8 bh = *(half8*)&sPH[cur][addr];
                    half8 bl = *(half8*)&sPL[cur][addr];
                    acc[jt] = __builtin_amdgcn_mfma_f32_16x16x32_f16(za[ks], bh, acc[jt], 0, 0, 0);
                    acc[jt] = __builtin_amdgcn_mfma_f32_16x16x32_f16(za[ks], bl, acc[jt], 0, 0, 0);
                    acc[jt] = __builtin_amdgcn_mfma_f32_16x16x32_f16(zb[ks], bh, acc[jt], 0, 0, 0);
                }
            }
            __syncthreads();  // drains prefetch (vmcnt) + reads (lgkm); 1 barrier/K-step
        }

        // ---- epilogue: s = acc + p2[col]; running (min, idx) per row r ----
#pragma unroll
        for (int jt = 0; jt < 8; ++jt) {
            int colg = bi * 128 + jt * 16 + c;
            float pv = p2[colg];
#pragma unroll
            for (int r = 0; r < 4; ++r) {
                float s = acc[jt][r] + pv;
                if (s < minv[r] || (s == minv[r] && colg < mini[r])) {
                    minv[r] = s;
                    mini[r] = colg;
                }
            }
        }
    }

    // ---- cross-lane reduce over the 16 col-slots (c); rows are (g,r) ----
#pragma unroll
    for (int r = 0; r < 4; ++r) {
        float v = minv[r];
        int id = mini[r];
#pragma unroll
        for (int mm = 1; mm < 16; mm <<= 1) {
            float ov = __shfl_xor(v, mm);
            int oi = __shfl_xor(id, mm);
            if (ov < v || (ov == v && oi < id)) { v = ov; id = oi; }
        }
        if (c == 0) {
            int rl = w * 16 + g * 4 + r;   // local row 0..127
            sFI[rl] = id;
            out[(size_t)N_ROWS * DIM + brow + rl] = (float)id;
        }
    }
    __syncthreads();

    // ---- winner prototype copy: 128 rows x 128 float4 ----
    const float4* pr4 = (const float4*)prot;
    float4* out4 = (float4*)out;
#pragma unroll 4
    for (int it = 0; it < 32; ++it) {
        int q = it * 512 + tid;
        int row = q >> 7, qk = q & 127;
        int fi = sFI[row];
        out4[(size_t)(brow + row) * 128 + qk] = pr4[(size_t)fi * 128 + qk];
    }
}

// ---------------- fallback (R1 kernel, used only if ws too small) -----------
__global__ __launch_bounds__(256) void som_fallback(const float* __restrict__ z,
                                                    const float* __restrict__ prot,
                                                    const float* __restrict__ p2,
                                                    float* __restrict__ out) {
    __shared__ __align__(16) _Float16 sZH[64 * 64];
    __shared__ __align__(16) _Float16 sZL[64 * 64];
    __shared__ __align__(16) _Float16 sPH[128 * 64];
    __shared__ __align__(16) _Float16 sPL[128 * 64];
    __shared__ float sMV[4][64];
    __shared__ int sMI[4][64];
    __shared__ int sFI[64];

    const int tid = threadIdx.x;
    const int w = tid >> 6, l = tid & 63;
    const int g = l >> 4, c = l & 15;
    const int brow = blockIdx.x * 64;
    const float4* z4 = (const float4*)z;
    const float4* pr4 = (const float4*)prot;

    float minv[4][4];
    int mini[4][4];
#pragma unroll
    for (int i = 0; i < 4; ++i)
#pragma unroll
        for (int r = 0; r < 4; ++r) { minv[i][r] = 3.0e38f; mini[i][r] = 0; }

    for (int bcol = 0; bcol < M_PROTO; bcol += 128) {
        f32x4 acc[4][2];
#pragma unroll
        for (int i = 0; i < 4; ++i)
#pragma unroll
            for (int jt = 0; jt < 2; ++jt) acc[i][jt] = (f32x4){0.f, 0.f, 0.f, 0.f};
        for (int kt = 0; kt < 8; ++kt) {
            __syncthreads();
#pragma unroll
            for (int it = 0; it < 4; ++it) {
                int q = it * 256 + tid;
                int row = q >> 4, kq = q & 15;
                float4 v = z4[(size_t)(brow + row) * 128 + kt * 16 + kq];
                float x0 = -2.f * v.x, x1 = -2.f * v.y, x2 = -2.f * v.z, x3 = -2.f * v.w;
                _Float16 h0 = (_Float16)x0, h1 = (_Float16)x1;
                _Float16 h2 = (_Float16)x2, h3 = (_Float16)x3;
                half4_t hv = {h0, h1, h2, h3};
                half4_t lv = {(_Float16)(x0 - (float)h0), (_Float16)(x1 - (float)h1),
                              (_Float16)(x2 - (float)h2), (_Float16)(x3 - (float)h3)};
                int addr = row * 64 + (((kq >> 1) ^ (row & 7)) << 3) + ((kq & 1) << 2);
                *(half4_t*)&sZH[addr] = hv;
                *(half4_t*)&sZL[addr] = lv;
            }
#pragma unroll
            for (int it = 0; it < 8; ++it) {
                int q = it * 256 + tid;
                int row = q >> 4, kq = q & 15;
                float4 v = pr4[(size_t)(bcol + row) * 128 + kt * 16 + kq];
                _Float16 h0 = (_Float16)v.x, h1 = (_Float16)v.y;
                _Float16 h2 = (_Float16)v.z, h3 = (_Float16)v.w;
                half4_t hv = {h0, h1, h2, h3};
                half4_t lv = {(_Float16)(v.x - (float)h0), (_Float16)(v.y - (float)h1),
                              (_Float16)(v.z - (float)h2), (_Float16)(v.w - (float)h3)};
                int addr = row * 64 + (((kq >> 1) ^ (row & 7)) << 3) + ((kq & 1) << 2);
                *(half4_t*)&sPH[addr] = hv;
                *(half4_t*)&sPL[addr] = lv;
            }
            __syncthreads();
#pragma unroll
            for (int ks = 0; ks < 2; ++ks) {
                half8 ah[4], al[4], bh[2], bl[2];
#pragma unroll
                for (int i = 0; i < 4; ++i) {
                    int row = i * 16 + c;
                    int addr = row * 64 + (((ks * 4 + g) ^ (row & 7)) << 3);
                    ah[i] = *(half8*)&sZH[addr];
                    al[i] = *(half8*)&sZL[addr];
                }
#pragma unroll
                for (int jt = 0; jt < 2; ++jt) {
                    int row = w * 32 + jt * 16 + c;
                    int addr = row * 64 + (((ks * 4 + g) ^ (row & 7)) << 3);
                    bh[jt] = *(half8*)&sPH[addr];
                    bl[jt] = *(half8*)&sPL[addr];
                }
#pragma unroll
                for (int i = 0; i < 4; ++i)
#pragma unroll
                    for (int jt = 0; jt < 2; ++jt) {
                        acc[i][jt] = __builtin_amdgcn_mfma_f32_16x16x32_f16(ah[i], bh[jt], acc[i][jt], 0, 0, 0);
                        acc[i][jt] = __builtin_amdgcn_mfma_f32_16x16x32_f16(ah[i], bl[jt], acc[i][jt], 0, 0, 0);
                        acc[i][jt] = __builtin_amdgcn_mfma_f32_16x16x32_f16(al[i], bh[jt], acc[i][jt], 0, 0, 0);
                    }
            }
        }
#pragma unroll
        for (int jt = 0; jt < 2; ++jt) {
            int colg = bcol + w * 32 + jt * 16 + c;
            float pv = p2[colg];
#pragma unroll
            for (int i = 0; i < 4; ++i)
#pragma unroll
                for (int r = 0; r < 4; ++r) {
                    float s = acc[i][jt][r] + pv;
                    if (s < minv[i][r] || (s == minv[i][r] && colg < mini[i][r])) {
                        minv[i][r] = s;
                        mini[i][r] = colg;
                    }
                }
        }
    }
#pragma unroll
    for (int i = 0; i < 4; ++i)
#pragma unroll
        for (int r = 0; r < 4; ++r) {
            float v = minv[i][r];
            int id = mini[i][r];
#pragma unroll
            for (int mm = 1; mm < 16; mm <<= 1) {
                float ov = __shfl_xor(v, mm);
                int oi = __shfl_xor(id, mm);
                if (ov < v || (ov == v && oi < id)) { v = ov; id = oi; }
            }
            if (c == 0) {
                sMV[w][i * 16 + g * 4 + r] = v;
                sMI[w][i * 16 + g * 4 + r] = id;
            }
        }
    __syncthreads();
    if (tid < 64) {
        float v = sMV[0][tid];
        int id = sMI[0][tid];
#pragma unroll
        for (int ww = 1; ww < 4; ++ww) {
            float ov = sMV[ww][tid];
            int oi = sMI[ww][tid];
            if (ov < v || (ov == v && oi < id)) { v = ov; id = oi; }
        }
        sFI[tid] = id;
        out[(size_t)N_ROWS * DIM + brow + tid] = (float)id;
    }
    __syncthreads();
    float4* out4 = (float4*)out;
#pragma unroll 4
    for (int it = 0; it < 32; ++it) {
        int q = it * 256 + tid;
        int row = q >> 7, qk = q & 127;
        int fi = sFI[row];
        out4[(size_t)(brow + row) * 128 + qk] = pr4[(size_t)fi * 128 + qk];
    }
}

extern "C" void kernel_launch(void* const* d_in, const int* in_sizes, int n_in,
                              void* d_out, int out_size, void* d_ws, size_t ws_size,
                              hipStream_t stream) {
    const float* z = (const float*)d_in[0];
    const float* prot = (const float*)d_in[1];
    char* base = (char*)d_ws;
    float* p2 = (float*)base;  // 16 KB

    const size_t NEED = 16384          // p2
                      + 8388608        // ph+pl (4 MB each)
                      + 67108864;      // zh+zl (32 MB each)

    p2_kernel<<<M_PROTO / 4, 256, 0, stream>>>(prot, p2);

    if (ws_size >= NEED) {
        _Float16* ph = (_Float16*)(base + 16384);
        _Float16* pl = (_Float16*)(base + 16384 + 4194304);
        half8* zh = (half8*)(base + 16384 + 8388608);
        half8* zl = (half8*)(base + 16384 + 8388608 + 33554432);
        conv_p_kernel<<<256, 256, 0, stream>>>(prot, ph, pl);
        conv_z_kernel<<<1024, 256, 0, stream>>>(z, zh, zl);
        som_main<<<N_ROWS / 128, 512, 0, stream>>>(zh, zl, ph, pl, p2, prot, (float*)d_out);
    } else {
        som_fallback<<<N_ROWS / 64, 256, 0, stream>>>(z, prot, p2, (float*)d_out);
    }
}